// Round 4
// baseline (156.035 us; speedup 1.0000x reference)
//
#include <hip/hip_runtime.h>
#include <cstdint>

#define BSZ 512   // batch
#define CSZ 256   // concepts

// ws layout (bytes):
//   bar      u32 @ 0    grid-barrier arrival counter
//   done     u32 @ 4    ticket counter for final reduce
//   acc_clip f32 @ 8
//   acc_bce  f32 @ 12
//   acc_mask f32 @ 16
//   acc_kl   f32 @ 20
//   packed   u64[BSZ*4] @ 64   (16 KB bit-packed concept rows)

__device__ __forceinline__ float wave_sum64(float v) {
    #pragma unroll
    for (int o = 32; o > 0; o >>= 1) v += __shfl_xor(v, o, 64);
    return v;
}

// 256-thread block sum: wave shuffle + 4-slot LDS combine (2 barriers total).
__device__ __forceinline__ float block_sum(float v, float* s4) {
    v = wave_sum64(v);
    if ((threadIdx.x & 63) == 0) s4[threadIdx.x >> 6] = v;
    __syncthreads();
    float r = (s4[0] + s4[1]) + (s4[2] + s4[3]);
    __syncthreads();
    return r;
}

__global__ void __launch_bounds__(256)
fused(const float* __restrict__ img,
      const float* __restrict__ txt,
      const float* __restrict__ clog,
      const float* __restrict__ csim,
      const int* __restrict__ mc,
      float* __restrict__ out,
      char* __restrict__ ws) {
    __shared__ unsigned long long wb[BSZ * 4];  // 16 KB
    __shared__ float sdat[BSZ];
    __shared__ float cdat[BSZ];
    __shared__ float s4[4];

    unsigned int* bar       = (unsigned int*)(ws + 0);
    unsigned int* done      = (unsigned int*)(ws + 4);
    float* acc_clip         = (float*)(ws + 8);
    float* acc_bce          = (float*)(ws + 12);
    float* acc_mask         = (float*)(ws + 16);
    float* acc_kl           = (float*)(ws + 20);
    unsigned long long* packed = (unsigned long long*)(ws + 64);

    int b = blockIdx.x, tid = threadIdx.x;

    // ---- Phase 0: bit-pack concepts (w=1 iff mc==1) and ARRIVE at barrier ----
    int m = mc[b * CSZ + tid];
    unsigned long long bal = __ballot(m == 1);
    if ((tid & 63) == 0)
        __hip_atomic_store(&packed[b * 4 + (tid >> 6)], bal,
                           __ATOMIC_RELAXED, __HIP_MEMORY_SCOPE_AGENT);
    __syncthreads();  // vmcnt(0) drain: all 4 packed stores complete
    if (tid == 0) { __threadfence(); atomicAdd(bar, 1u); }

    // ---- Phase 1: clip rows + BCE (independent work hides barrier arrivals) ----
    const float* ri = img + (size_t)b * BSZ;
    const float* rt = txt + (size_t)b * BSZ;
    // no max-subtraction: |x| <= ~15 -> exp/sum safely in fp32; threshold 0.255 abs
    float Si = block_sum(expf(ri[tid]) + expf(ri[tid + 256]), s4);
    float St = block_sum(expf(rt[tid]) + expf(rt[tid + 256]), s4);
    float x = clog[b * CSZ + tid];
    float maskf = (m != -1) ? 1.0f : 0.0f;
    float tt = (m == 1) ? 1.0f : 0.0f;
    float loss = (fmaxf(x, 0.0f) + log1pf(expf(-fabsf(x))) - x * tt) * maskf;
    float Ls = block_sum(loss, s4);
    float Ms = block_sum(maskf, s4);
    if (tid == 0) {
        atomicAdd(acc_clip, (logf(Si) - ri[b]) + (logf(St) - rt[b]));
        atomicAdd(acc_bce, Ls);
        atomicAdd(acc_mask, Ms);
    }

    // ---- Grid barrier WAIT (packed rows all published) ----
    if (tid == 0) {
        while (__hip_atomic_load(bar, __ATOMIC_RELAXED, __HIP_MEMORY_SCOPE_AGENT)
               < (unsigned)gridDim.x)
            __builtin_amdgcn_s_sleep(2);
    }
    __syncthreads();

    // ---- Phase 2: Jaccard sims via popcount + softmax targets + KL ----
    for (int k = tid; k < BSZ * 4; k += 256)
        wb[k] = __hip_atomic_load(&packed[k], __ATOMIC_RELAXED, __HIP_MEMORY_SCOPE_AGENT);
    __syncthreads();
    unsigned long long a0 = wb[b * 4 + 0], a1 = wb[b * 4 + 1];
    unsigned long long a2 = wb[b * 4 + 2], a3 = wb[b * 4 + 3];
    #pragma unroll 2
    for (int j = tid; j < BSZ; j += 256) {
        unsigned long long b0 = wb[j * 4 + 0], b1 = wb[j * 4 + 1];
        unsigned long long b2 = wb[j * 4 + 2], b3 = wb[j * 4 + 3];
        int inter = __popcll(a0 & b0) + __popcll(a1 & b1) + __popcll(a2 & b2) + __popcll(a3 & b3);
        int uni   = __popcll(a0 | b0) + __popcll(a1 | b1) + __popcll(a2 | b2) + __popcll(a3 | b3);
        float sim = (uni > 0) ? ((float)inter / (float)uni) : 0.0f;
        sdat[j] = sim * (1.0f / 0.07f);
        cdat[j] = csim[(size_t)b * BSZ + j];
    }
    __syncthreads();
    float s0 = sdat[tid], s1 = sdat[tid + 256];
    float c0 = cdat[tid], c1 = cdat[tid + 256];
    float Zs = block_sum(expf(s0) + expf(s1), s4);   // s in [0, 14.3] -> fp32 safe
    float Zc = block_sum(expf(c0) + expf(c1), s4);
    float lse_s = logf(Zs), lse_c = logf(Zc);
    float t0 = expf(s0 - lse_s), t1 = expf(s1 - lse_s);
    float kl = block_sum(t0 * ((s0 - lse_s) - (c0 - lse_c)) +
                         t1 * ((s1 - lse_s) - (c1 - lse_c)), s4);

    // ---- Phase 3: ticket; last block's tid0 finalizes ----
    if (tid == 0) {
        atomicAdd(acc_kl, kl);
        __threadfence();
        unsigned int ticket = atomicAdd(done, 1u);
        if (ticket == (unsigned)gridDim.x - 1) {
            float c  = atomicAdd(acc_clip, 0.0f);   // coherent reads
            float bc = atomicAdd(acc_bce, 0.0f);
            float mk = atomicAdd(acc_mask, 0.0f);
            float k2 = atomicAdd(acc_kl, 0.0f);
            out[0] = c / (2.0f * BSZ)
                   + 0.5f * (bc / (mk + 1e-8f))
                   + 0.3f * (k2 / (float)BSZ);
        }
    }
}

extern "C" void kernel_launch(void* const* d_in, const int* in_sizes, int n_in,
                              void* d_out, int out_size, void* d_ws, size_t ws_size,
                              hipStream_t stream) {
    const float* logits_img = (const float*)d_in[0];   // [512,512]
    const float* logits_txt = (const float*)d_in[1];   // [512,512]
    const float* clog       = (const float*)d_in[2];   // [512,256]
    const float* csim       = (const float*)d_in[3];   // [512,512]
    const int*   mc         = (const int*)d_in[4];     // [512,256]
    float* out = (float*)d_out;
    char* ws = (char*)d_ws;

    // zero the 6 control/accumulator words (ws arrives poisoned 0xAA)
    hipMemsetAsync(ws, 0, 64, stream);

    void* args[] = {(void*)&logits_img, (void*)&logits_txt, (void*)&clog,
                    (void*)&csim, (void*)&mc, (void*)&out, (void*)&ws};
    hipLaunchCooperativeKernel((const void*)fused, dim3(BSZ), dim3(256),
                               args, 0, stream);
}

// Round 5
// 80.661 us; speedup vs baseline: 1.9344x; 1.9344x over previous
//
#include <hip/hip_runtime.h>
#include <cstdint>

#define BSZ 512   // batch
#define CSZ 256   // concepts

// ws layout (bytes):
//   ctrl   : u32[256] @ 0      -- dc[i] at byte 64*i (i<8), d2 at byte 512; zeroed by prep block 0
//   pc     : f32[1024] @ 1024  -- clip partials (img rows 0..511, txt rows 512..1023)
//   pb     : f32[512]  @ 5120  -- bce sum per row
//   pm     : f32[512]  @ 7168  -- mask count per row
//   pk     : f32[512]  @ 9216  -- kl partial per row (agent-scope atomic stores)
//   packed : u64[2048] @ 12288 -- bit-packed concept rows (16 KB)

__device__ __forceinline__ float wave_sum64(float v) {
    #pragma unroll
    for (int o = 32; o > 0; o >>= 1) v += __shfl_xor(v, o, 64);
    return v;
}

// 256-thread block sum: wave shuffle + 4-slot LDS combine (2 barriers total).
__device__ __forceinline__ float block_sum(float v, float* s4) {
    v = wave_sum64(v);
    if ((threadIdx.x & 63) == 0) s4[threadIdx.x >> 6] = v;
    __syncthreads();
    float r = (s4[0] + s4[1]) + (s4[2] + s4[3]);
    __syncthreads();
    return r;
}

// Kernel A: 1536 blocks, one row-task each.
//   [0,512)    : img row softmax -> pc[g]
//   [512,1024) : txt row softmax -> pc[g]
//   [1024,1536): concept BCE + bit-pack -> pb/pm/packed
__global__ void __launch_bounds__(256)
prep(const float* __restrict__ img, const float* __restrict__ txt,
     const float* __restrict__ clog, const int* __restrict__ mc,
     char* __restrict__ ws) {
    __shared__ float s4[4];
    int g = blockIdx.x, tid = threadIdx.x;
    float* pc = (float*)(ws + 1024);
    float* pb = (float*)(ws + 5120);
    float* pm = (float*)(ws + 7168);
    unsigned long long* packed = (unsigned long long*)(ws + 12288);

    if (g == 0) ((unsigned int*)ws)[tid] = 0u;  // zero 1 KB control region

    if (g < 1024) {
        int b = g & 511;
        const float* row = ((g < 512) ? img : txt) + (size_t)b * BSZ;
        float2 v = ((const float2*)row)[tid];
        // no max-subtraction: |x| <= ~15 -> fp32-safe (validated R3, absmax 0)
        float S = block_sum(expf(v.x) + expf(v.y), s4);
        if (tid == 0) pc[g] = logf(S) - row[b];
    } else {
        int b = g - 1024;
        int m = mc[b * CSZ + tid];
        float x = clog[b * CSZ + tid];
        float maskf = (m != -1) ? 1.0f : 0.0f;
        float t = (m == 1) ? 1.0f : 0.0f;
        float loss = (fmaxf(x, 0.0f) + log1pf(expf(-fabsf(x))) - x * t) * maskf;
        float Ls = block_sum(loss, s4);
        float Ms = block_sum(maskf, s4);
        if (tid == 0) { pb[b] = Ls; pm[b] = Ms; }
        unsigned long long bal = __ballot(m == 1);
        if ((tid & 63) == 0) packed[b * 4 + (tid >> 6)] = bal;
    }
}

// Kernel B: 512 blocks, one sim/KL row each; hierarchical-ticket finalize.
__global__ void __launch_bounds__(256)
simfin(const float* __restrict__ csim, char* __restrict__ ws,
       float* __restrict__ out) {
    __shared__ unsigned long long wb[BSZ * 4];  // 16 KB
    __shared__ float s4[4];
    __shared__ int islast;

    unsigned int* dc = (unsigned int*)ws;              // 8 counters, 64-B stride
    unsigned int* d2 = (unsigned int*)(ws + 512);
    float* pc = (float*)(ws + 1024);
    float* pb = (float*)(ws + 5120);
    float* pm = (float*)(ws + 7168);
    float* pk = (float*)(ws + 9216);
    unsigned long long* packed = (unsigned long long*)(ws + 12288);

    int b = blockIdx.x, tid = threadIdx.x;

    // packed/pc/pb/pm came from kernel A: kernel boundary = visibility; plain loads.
    for (int k = tid; k < BSZ * 4; k += 256) wb[k] = packed[k];
    float2 cv = ((const float2*)(csim + (size_t)b * BSZ))[tid];  // elements 2t, 2t+1
    __syncthreads();

    unsigned long long a0 = wb[b * 4 + 0], a1 = wb[b * 4 + 1];
    unsigned long long a2 = wb[b * 4 + 2], a3 = wb[b * 4 + 3];
    float s01[2];
    #pragma unroll
    for (int it = 0; it < 2; ++it) {
        int j = 2 * tid + it;                           // same elements as cv
        unsigned long long b0 = wb[j * 4 + 0], b1 = wb[j * 4 + 1];
        unsigned long long b2 = wb[j * 4 + 2], b3 = wb[j * 4 + 3];
        int inter = __popcll(a0 & b0) + __popcll(a1 & b1) + __popcll(a2 & b2) + __popcll(a3 & b3);
        int uni   = __popcll(a0 | b0) + __popcll(a1 | b1) + __popcll(a2 | b2) + __popcll(a3 | b3);
        float sim = (uni > 0) ? ((float)inter / (float)uni) : 0.0f;
        s01[it] = sim * (1.0f / 0.07f);                 // in [0, 14.3] -> fp32 safe
    }
    float s0 = s01[0], s1 = s01[1];
    float c0 = cv.x, c1 = cv.y;
    float Zs = block_sum(expf(s0) + expf(s1), s4);
    float Zc = block_sum(expf(c0) + expf(c1), s4);
    float lse_s = logf(Zs), lse_c = logf(Zc);
    float t0 = expf(s0 - lse_s), t1 = expf(s1 - lse_s);
    float kl = block_sum(t0 * ((s0 - lse_s) - (c0 - lse_c)) +
                         t1 * ((s1 - lse_s) - (c1 - lse_c)), s4);

    if (tid == 0) {
        // publish kl partial at agent scope (cross-XCD visible; pattern proven in R3)
        __hip_atomic_store(&pk[b], kl, __ATOMIC_RELAXED, __HIP_MEMORY_SCOPE_AGENT);
        __threadfence();
        islast = 0;
        unsigned t1k = atomicAdd(&dc[(b & 7) * 16], 1u);   // 64 per slot
        if (t1k == 63u) {
            unsigned t2k = atomicAdd(d2, 1u);
            if (t2k == 7u) islast = 1;
        }
    }
    __syncthreads();

    if (islast) {
        __threadfence();
        float sc = 0.0f, sb = 0.0f, sm = 0.0f, sk = 0.0f;
        for (int k = tid; k < 2 * BSZ; k += 256) sc += pc[k];
        for (int k = tid; k < BSZ; k += 256) {
            sb += pb[k];
            sm += pm[k];
            sk += __hip_atomic_load(&pk[k], __ATOMIC_RELAXED, __HIP_MEMORY_SCOPE_AGENT);
        }
        sc = block_sum(sc, s4);
        sb = block_sum(sb, s4);
        sm = block_sum(sm, s4);
        sk = block_sum(sk, s4);
        if (tid == 0) {
            out[0] = sc / (2.0f * BSZ)
                   + 0.5f * (sb / (sm + 1e-8f))
                   + 0.3f * (sk / (float)BSZ);
        }
    }
}

extern "C" void kernel_launch(void* const* d_in, const int* in_sizes, int n_in,
                              void* d_out, int out_size, void* d_ws, size_t ws_size,
                              hipStream_t stream) {
    const float* logits_img = (const float*)d_in[0];   // [512,512]
    const float* logits_txt = (const float*)d_in[1];   // [512,512]
    const float* clog       = (const float*)d_in[2];   // [512,256]
    const float* csim       = (const float*)d_in[3];   // [512,512]
    const int*   mc         = (const int*)d_in[4];     // [512,256]
    float* out = (float*)d_out;
    char* ws = (char*)d_ws;

    prep<<<3 * BSZ, 256, 0, stream>>>(logits_img, logits_txt, clog, mc, ws);
    simfin<<<BSZ, 256, 0, stream>>>(csim, ws, out);
}

// Round 6
// 79.417 us; speedup vs baseline: 1.9647x; 1.0157x over previous
//
#include <hip/hip_runtime.h>
#include <cstdint>

#define BSZ 512   // batch
#define CSZ 256   // concepts

// ws layout (bytes):
//   ctrl   : u32[256] @ 0      -- dc[i] at byte 64*i (i<8), d2 at byte 512; zeroed by prep block 0
//   pc     : f32[1024] @ 1024  -- clip partials (img rows 0..511, txt rows 512..1023)
//   pb     : f32[512]  @ 5120  -- bce sum per row
//   pm     : f32[512]  @ 7168  -- mask count per row
//   pk     : f32[512]  @ 9216  -- kl partial per row (agent-scope atomic stores)
//   packed : u64[2048] @ 12288 -- bit-packed concept rows (16 KB)

__device__ __forceinline__ float wave_sum64(float v) {
    #pragma unroll
    for (int o = 32; o > 0; o >>= 1) v += __shfl_xor(v, o, 64);
    return v;
}

// 256-thread block sum: wave shuffle + 4-slot LDS combine (2 barriers total).
__device__ __forceinline__ float block_sum(float v, float* s4) {
    v = wave_sum64(v);
    if ((threadIdx.x & 63) == 0) s4[threadIdx.x >> 6] = v;
    __syncthreads();
    float r = (s4[0] + s4[1]) + (s4[2] + s4[3]);
    __syncthreads();
    return r;
}

// Kernel A: 1536 blocks, one row-task each.
//   [0,512)    : img row softmax -> pc[g]
//   [512,1024) : txt row softmax -> pc[g]
//   [1024,1536): concept BCE + bit-pack -> pb/pm/packed
__global__ void __launch_bounds__(256)
prep(const float* __restrict__ img, const float* __restrict__ txt,
     const float* __restrict__ clog, const int* __restrict__ mc,
     char* __restrict__ ws) {
    __shared__ float s4[4];
    int g = blockIdx.x, tid = threadIdx.x;
    float* pc = (float*)(ws + 1024);
    float* pb = (float*)(ws + 5120);
    float* pm = (float*)(ws + 7168);
    unsigned long long* packed = (unsigned long long*)(ws + 12288);

    if (g == 0) ((unsigned int*)ws)[tid] = 0u;  // zero 1 KB control region

    if (g < 1024) {
        int b = g & 511;
        const float* row = ((g < 512) ? img : txt) + (size_t)b * BSZ;
        float2 v = ((const float2*)row)[tid];
        // no max-subtraction: |x| <= ~15 -> fp32-safe (validated R3/R4, absmax 0)
        float S = block_sum(expf(v.x) + expf(v.y), s4);
        if (tid == 0) pc[g] = logf(S) - row[b];
    } else {
        int b = g - 1024;
        int m = mc[b * CSZ + tid];
        float x = clog[b * CSZ + tid];
        float maskf = (m != -1) ? 1.0f : 0.0f;
        float t = (m == 1) ? 1.0f : 0.0f;
        float loss = (fmaxf(x, 0.0f) + log1pf(expf(-fabsf(x))) - x * t) * maskf;
        float Ls = block_sum(loss, s4);
        float Ms = block_sum(maskf, s4);
        if (tid == 0) { pb[b] = Ls; pm[b] = Ms; }
        unsigned long long bal = __ballot(m == 1);
        if ((tid & 63) == 0) packed[b * 4 + (tid >> 6)] = bal;
    }
}

// Kernel B: 512 blocks, one sim/KL row each; no LDS staging (direct L2-hot
// loads: thread t consumes only packed rows 2t and 2t+1; a-row is a
// wave-uniform broadcast). Hierarchical-ticket finalize.
__global__ void __launch_bounds__(256)
simfin(const float* __restrict__ csim, char* __restrict__ ws,
       float* __restrict__ out) {
    __shared__ float s4[4];
    __shared__ int islast;

    unsigned int* dc = (unsigned int*)ws;              // 8 counters, 64-B stride
    unsigned int* d2 = (unsigned int*)(ws + 512);
    float* pc = (float*)(ws + 1024);
    float* pb = (float*)(ws + 5120);
    float* pm = (float*)(ws + 7168);
    float* pk = (float*)(ws + 9216);
    const unsigned long long* packed = (const unsigned long long*)(ws + 12288);

    int b = blockIdx.x, tid = threadIdx.x;

    // a-row (row b): same address for all lanes -> broadcast fetch
    unsigned long long a0 = packed[b * 4 + 0], a1 = packed[b * 4 + 1];
    unsigned long long a2 = packed[b * 4 + 2], a3 = packed[b * 4 + 3];
    // b-rows 2t and 2t+1: 64 B/thread, coalesced 16-B loads
    const ulonglong2* p2 = (const ulonglong2*)packed;
    ulonglong2 r0 = p2[4 * tid + 0], r1 = p2[4 * tid + 1];   // row 2t
    ulonglong2 r2 = p2[4 * tid + 2], r3 = p2[4 * tid + 3];   // row 2t+1
    float2 cv = ((const float2*)(csim + (size_t)b * BSZ))[tid];

    int i0 = __popcll(a0 & r0.x) + __popcll(a1 & r0.y) + __popcll(a2 & r1.x) + __popcll(a3 & r1.y);
    int u0 = __popcll(a0 | r0.x) + __popcll(a1 | r0.y) + __popcll(a2 | r1.x) + __popcll(a3 | r1.y);
    int i1 = __popcll(a0 & r2.x) + __popcll(a1 & r2.y) + __popcll(a2 & r3.x) + __popcll(a3 & r3.y);
    int u1 = __popcll(a0 | r2.x) + __popcll(a1 | r2.y) + __popcll(a2 | r3.x) + __popcll(a3 | r3.y);
    float s0 = ((u0 > 0) ? ((float)i0 / (float)u0) : 0.0f) * (1.0f / 0.07f);
    float s1 = ((u1 > 0) ? ((float)i1 / (float)u1) : 0.0f) * (1.0f / 0.07f);
    float c0 = cv.x, c1 = cv.y;

    float Zs = block_sum(expf(s0) + expf(s1), s4);   // s in [0,14.3] -> fp32 safe
    float Zc = block_sum(expf(c0) + expf(c1), s4);
    float lse_s = logf(Zs), lse_c = logf(Zc);
    float t0 = expf(s0 - lse_s), t1 = expf(s1 - lse_s);
    float kl = block_sum(t0 * ((s0 - lse_s) - (c0 - lse_c)) +
                         t1 * ((s1 - lse_s) - (c1 - lse_c)), s4);

    if (tid == 0) {
        // publish kl partial at agent scope (cross-XCD visible; proven pattern)
        __hip_atomic_store(&pk[b], kl, __ATOMIC_RELAXED, __HIP_MEMORY_SCOPE_AGENT);
        __threadfence();
        islast = 0;
        unsigned t1k = atomicAdd(&dc[(b & 7) * 16], 1u);   // 64 arrivals per slot
        if (t1k == 63u) {
            unsigned t2k = atomicAdd(d2, 1u);
            if (t2k == 7u) islast = 1;
        }
    }
    __syncthreads();

    if (islast) {
        __threadfence();
        float sc = 0.0f, sb = 0.0f, sm = 0.0f, sk = 0.0f;
        for (int k = tid; k < 2 * BSZ; k += 256) sc += pc[k];
        for (int k = tid; k < BSZ; k += 256) {
            sb += pb[k];
            sm += pm[k];
            sk += __hip_atomic_load(&pk[k], __ATOMIC_RELAXED, __HIP_MEMORY_SCOPE_AGENT);
        }
        sc = block_sum(sc, s4);
        sb = block_sum(sb, s4);
        sm = block_sum(sm, s4);
        sk = block_sum(sk, s4);
        if (tid == 0) {
            out[0] = sc / (2.0f * BSZ)
                   + 0.5f * (sb / (sm + 1e-8f))
                   + 0.3f * (sk / (float)BSZ);
        }
    }
}

extern "C" void kernel_launch(void* const* d_in, const int* in_sizes, int n_in,
                              void* d_out, int out_size, void* d_ws, size_t ws_size,
                              hipStream_t stream) {
    const float* logits_img = (const float*)d_in[0];   // [512,512]
    const float* logits_txt = (const float*)d_in[1];   // [512,512]
    const float* clog       = (const float*)d_in[2];   // [512,256]
    const float* csim       = (const float*)d_in[3];   // [512,512]
    const int*   mc         = (const int*)d_in[4];     // [512,256]
    float* out = (float*)d_out;
    char* ws = (char*)d_ws;

    prep<<<3 * BSZ, 256, 0, stream>>>(logits_img, logits_txt, clog, mc, ws);
    simfin<<<BSZ, 256, 0, stream>>>(csim, ws, out);
}